// Round 18
// baseline (516.667 us; speedup 1.0000x reference)
//
#include <hip/hip_runtime.h>
#include <hip/hip_fp16.h>

#define NN 100000
#define NE 1600000
#define ET (NE + NN)   // edges + self-loops = 1,700,000
#define BKW 512                      // bucket width (nodes); dst>>9
#define NBK ((NN + BKW - 1) / BKW)   // 196 buckets
#define LCOL_CAP 12288               // max edges/bucket
#define EPB 16384                    // edges per scatter block

typedef _Float16 half8_t __attribute__((ext_vector_type(8)));
typedef float f32x4_t __attribute__((ext_vector_type(4)));

// ---- ordered-uint encoding for float atomicMax (bijective, monotone) ----
__device__ __forceinline__ unsigned enc_f32(float v) {
    unsigned b = __float_as_uint(v);
    return b ^ ((b & 0x80000000u) ? 0xFFFFFFFFu : 0x80000000u);
}
__device__ __forceinline__ float dec_f32(unsigned u) {
    unsigned b = (u & 0x80000000u) ? (u ^ 0x80000000u) : ~u;
    return __uint_as_float(b);
}

// ============================ dense layers ============================

// h0 = relu(x @ W_in + b_in), fp16 output. W_in staged in LDS.
__global__ __launch_bounds__(256) void lin_relu2h(const float* __restrict__ x,
                                                  const float* __restrict__ W,
                                                  const float* __restrict__ b,
                                                  __half* __restrict__ h) {
    __shared__ float Wl[256 * 32];
    int t = threadIdx.x;
    for (int j = 0; j < 8; ++j) {
        int f = t + 256 * j;
        *(float4*)&Wl[f * 4] = *(const float4*)(W + f * 4);
    }
    __syncthreads();

    int row = (blockIdx.x * 256 + t) >> 3;
    int c0  = (t & 7) * 4;
    const float* xr = x + (long long)row * 256;
    float4 acc = {0.f, 0.f, 0.f, 0.f};
    for (int k4 = 0; k4 < 64; ++k4) {
        float4 xv = *(const float4*)(xr + k4 * 4);
        float4 w0 = *(const float4*)&Wl[(k4 * 4 + 0) * 32 + c0];
        float4 w1 = *(const float4*)&Wl[(k4 * 4 + 1) * 32 + c0];
        float4 w2 = *(const float4*)&Wl[(k4 * 4 + 2) * 32 + c0];
        float4 w3 = *(const float4*)&Wl[(k4 * 4 + 3) * 32 + c0];
        acc.x += xv.x * w0.x + xv.y * w1.x + xv.z * w2.x + xv.w * w3.x;
        acc.y += xv.x * w0.y + xv.y * w1.y + xv.z * w2.y + xv.w * w3.y;
        acc.z += xv.x * w0.z + xv.y * w1.z + xv.z * w2.z + xv.w * w3.z;
        acc.w += xv.x * w0.w + xv.y * w1.w + xv.z * w2.w + xv.w * w3.w;
    }
    float4 bv = *(const float4*)(b + c0);
    __half2 p0 = __floats2half2_rn(fmaxf(acc.x + bv.x, 0.f), fmaxf(acc.y + bv.y, 0.f));
    __half2 p1 = __floats2half2_rn(fmaxf(acc.z + bv.z, 0.f), fmaxf(acc.w + bv.w, 0.f));
    uint2 pk;
    pk.x = *(unsigned*)&p0;
    pk.y = *(unsigned*)&p1;
    *(uint2*)(h + (long long)row * 32 + c0) = pk;
}

// ---- pack W [K][128] f32 into per-lane MFMA B-fragment order (fp16), K = KS*32 ----
template<int KS>
__global__ __launch_bounds__(256) void wf_prep(const float* __restrict__ W,
                                               _Float16* __restrict__ Wf) {
    int id = blockIdx.x * 256 + threadIdx.x;     // < 8*KS*64
    if (id >= 8 * KS * 64) return;
    int lane = id & 63;
    int q = id >> 6;
    int ks = q % KS;
    int n = q / KS;
    int col = n * 16 + (lane & 15);
    int k0 = ks * 32 + ((lane >> 4) << 3);
    _Float16 tmp[8];
    #pragma unroll
    for (int j = 0; j < 8; ++j) tmp[j] = (_Float16)W[(k0 + j) * 128 + col];
    *(half8_t*)(Wf + (size_t)id * 8) = *(half8_t*)tmp;
}

// ---- MFMA gemm, K = KS*32, N=128. 128 rows/block, 4 waves x 32 rows. ----
template<int KS>
__global__ __launch_bounds__(256) void gemm_mfma(const __half* __restrict__ ah,
                                                 const _Float16* __restrict__ Wf,
                                                 const float* __restrict__ asrc,
                                                 const float* __restrict__ adst,
                                                 __half* __restrict__ hph,
                                                 float* __restrict__ es,
                                                 float* __restrict__ ed,
                                                 unsigned* __restrict__ mxl) {
    __shared__ unsigned lmx[8];
    int t = threadIdx.x;
    if (t < 8) lmx[t] = 0u;
    __syncthreads();

    const int K = KS * 32;
    int lane = t & 63, wid = t >> 6;
    int li = lane & 15, lg = lane >> 4;
    int base = blockIdx.x * 128 + wid * 32;
    int r0 = base + li, r1 = r0 + 16;
    long long r0c = min(r0, NN - 1), r1c = min(r1, NN - 1);
    const _Float16* A = (const _Float16*)ah;

    f32x4_t acc[2][8];
    #pragma unroll
    for (int m = 0; m < 2; ++m)
        #pragma unroll
        for (int n = 0; n < 8; ++n) acc[m][n] = (f32x4_t){0.f, 0.f, 0.f, 0.f};

    #pragma unroll
    for (int ks = 0; ks < KS; ++ks) {
        half8_t a0 = *(const half8_t*)(A + r0c * K + ks * 32 + lg * 8);
        half8_t a1 = *(const half8_t*)(A + r1c * K + ks * 32 + lg * 8);
        #pragma unroll
        for (int n = 0; n < 8; ++n) {
            half8_t b = *(const half8_t*)(Wf + (size_t)((n * KS + ks) * 64 + lane) * 8);
            acc[0][n] = __builtin_amdgcn_mfma_f32_16x16x32_f16(a0, b, acc[0][n], 0, 0, 0);
            acc[1][n] = __builtin_amdgcn_mfma_f32_16x16x32_f16(a1, b, acc[1][n], 0, 0, 0);
        }
    }

    float as_lo[4], as_hi[4], ad_lo[4], ad_hi[4];
    #pragma unroll
    for (int h = 0; h < 4; ++h) {
        as_lo[h] = asrc[h * 32 + li];
        as_hi[h] = asrc[h * 32 + 16 + li];
        ad_lo[h] = adst[h * 32 + li];
        ad_hi[h] = adst[h * 32 + 16 + li];
    }

    float smax[4] = {-1e30f, -1e30f, -1e30f, -1e30f};
    float dmax[4] = {-1e30f, -1e30f, -1e30f, -1e30f};
    #pragma unroll
    for (int m = 0; m < 2; ++m) {
        #pragma unroll
        for (int r = 0; r < 4; ++r) {
            int gr = base + m * 16 + lg * 4 + r;
            bool valid = gr < NN;
            float ps[4], pd[4];
            #pragma unroll
            for (int h = 0; h < 4; ++h) {
                float va = acc[m][2 * h][r];
                float vb = acc[m][2 * h + 1][r];
                if (valid) {
                    hph[(long long)gr * 128 + h * 32 + li] = __float2half(va);
                    hph[(long long)gr * 128 + h * 32 + 16 + li] = __float2half(vb);
                }
                ps[h] = va * as_lo[h] + vb * as_hi[h];
                pd[h] = va * ad_lo[h] + vb * ad_hi[h];
            }
            #pragma unroll
            for (int off = 1; off < 16; off <<= 1) {
                #pragma unroll
                for (int h = 0; h < 4; ++h) {
                    ps[h] += __shfl_xor(ps[h], off);
                    pd[h] += __shfl_xor(pd[h], off);
                }
            }
            if (li == 0 && valid) {
                #pragma unroll
                for (int h = 0; h < 4; ++h) {
                    es[gr * 4 + h] = ps[h];
                    ed[gr * 4 + h] = pd[h];
                    smax[h] = fmaxf(smax[h], ps[h]);
                    dmax[h] = fmaxf(dmax[h], pd[h]);
                }
            }
        }
    }
    if (li == 0) {
        #pragma unroll
        for (int h = 0; h < 4; ++h) {
            atomicMax(&lmx[h], enc_f32(smax[h]));
            atomicMax(&lmx[4 + h], enc_f32(dmax[h]));
        }
    }
    __syncthreads();
    if (t < 8) atomicMax(mxl + t, lmx[t]);
}

// ================== CSR build via 2-level bucket sort (once) ==================

__global__ __launch_bounds__(256) void bucket_hist(const int* __restrict__ ei,
                                                   int* __restrict__ bhist) {
    __shared__ int lh[NBK];
    int t = threadIdx.x;
    for (int i = t; i < NBK; i += 256) lh[i] = 0;
    __syncthreads();
    for (long long e = (long long)blockIdx.x * 256 + t; e < ET; e += (long long)gridDim.x * 256) {
        int dst = (e < NE) ? ei[NE + e] : (int)(e - NE);
        atomicAdd(&lh[dst >> 9], 1);
    }
    __syncthreads();
    for (int i = t; i < NBK; i += 256) if (lh[i]) atomicAdd(&bhist[i], lh[i]);
}

__global__ __launch_bounds__(256) void bucket_scan(const int* __restrict__ bhist,
                                                   int* __restrict__ bbase,
                                                   int* __restrict__ bcur) {
    __shared__ int ls[256];
    int t = threadIdx.x;
    int v = (t < NBK) ? bhist[t] : 0;
    ls[t] = v;
    __syncthreads();
    for (int off = 1; off < 256; off <<= 1) {
        int u = (t >= off) ? ls[t - off] : 0;
        __syncthreads();
        ls[t] += u;
        __syncthreads();
    }
    if (t < NBK) { int b0 = ls[t] - v; bbase[t] = b0; bcur[t] = b0; }
    if (t == 0) bbase[NBK] = ET;
}

__global__ __launch_bounds__(256) void bucket_scatter(const int* __restrict__ ei,
                                                      int* __restrict__ bcur,
                                                      unsigned* __restrict__ brec) {
    __shared__ int lcnt[NBK];
    __shared__ int lbase[NBK];
    int t = threadIdx.x;
    long long e0 = (long long)blockIdx.x * EPB;
    for (int i = t; i < NBK; i += 256) lcnt[i] = 0;
    __syncthreads();
    for (int j = 0; j < EPB / 256; ++j) {
        long long e = e0 + j * 256 + t;
        if (e < ET) {
            int dst = (e < NE) ? ei[NE + e] : (int)(e - NE);
            atomicAdd(&lcnt[dst >> 9], 1);
        }
    }
    __syncthreads();
    for (int i = t; i < NBK; i += 256) {
        int c = lcnt[i];
        lbase[i] = c ? atomicAdd(&bcur[i], c) : 0;
        lcnt[i] = 0;
    }
    __syncthreads();
    for (int j = 0; j < EPB / 256; ++j) {
        long long e = e0 + j * 256 + t;
        if (e < ET) {
            int src, dst;
            if (e < NE) { src = ei[e]; dst = ei[NE + e]; }
            else        { src = dst = (int)(e - NE); }
            int b = dst >> 9;
            int off = atomicAdd(&lcnt[b], 1);
            brec[lbase[b] + off] = ((unsigned)(dst & 511) << 17) | (unsigned)src;
        }
    }
}

__global__ __launch_bounds__(256) void bucket_csr(const unsigned* __restrict__ brec,
                                                  const int* __restrict__ bbase,
                                                  int* __restrict__ row_ptr,
                                                  int* __restrict__ col) {
    __shared__ int ldeg[BKW];
    __shared__ int lrp[BKW + 1];
    __shared__ int lcur[BKW];
    __shared__ int ls[256];
    __shared__ int lcol[LCOL_CAP];
    int t = threadIdx.x, b = blockIdx.x;
    int rbeg = bbase[b], rend = bbase[b + 1];
    int cnt = rend - rbeg;
    for (int i = t; i < BKW; i += 256) ldeg[i] = 0;
    __syncthreads();
    for (int i = t; i < cnt; i += 256) {
        unsigned r = brec[rbeg + i];
        atomicAdd(&ldeg[r >> 17], 1);
    }
    __syncthreads();
    int a0 = ldeg[2 * t], a1 = ldeg[2 * t + 1];
    int pl = a0 + a1;
    ls[t] = pl;
    __syncthreads();
    for (int off = 1; off < 256; off <<= 1) {
        int u = (t >= off) ? ls[t - off] : 0;
        __syncthreads();
        ls[t] += u;
        __syncthreads();
    }
    int eb = ls[t] - pl;
    lrp[2 * t] = eb;
    lrp[2 * t + 1] = eb + a0;
    lcur[2 * t] = eb;
    lcur[2 * t + 1] = eb + a0;
    if (t == 255) lrp[BKW] = ls[255];
    __syncthreads();
    int gn0 = b * BKW;
    int nnb = min(BKW, NN - gn0);
    for (int i = t; i <= nnb; i += 256) row_ptr[gn0 + i] = rbeg + lrp[i];
    for (int i = t; i < cnt; i += 256) {
        unsigned r = brec[rbeg + i];
        int pos = atomicAdd(&lcur[r >> 17], 1);
        lcol[pos] = (int)(r & 0x1FFFFu);
    }
    __syncthreads();
    for (int i = t; i < cnt; i += 256) col[rbeg + i] = lcol[i];
}

// ==================== single-pass softmax-aggregate (fp16 gather) ====================
// 16 lanes/node, lane owns 8 dims. int4 col loads (aligned main loop + scalar pro/epi).
__global__ __launch_bounds__(256) void gat_aggregate6(
        const int* __restrict__ row_ptr, const int* __restrict__ col,
        const float* __restrict__ es, const float* __restrict__ ed,
        const unsigned* __restrict__ mx, const __half* __restrict__ hph,
        const float* __restrict__ b, float* __restrict__ outf,
        __half* __restrict__ outh) {
    int tid = blockIdx.x * 256 + threadIdx.x;
    int n = tid >> 4;
    int t = tid & 15;
    if (n >= NN) return;
    int head = t >> 2;
    int beg = row_ptr[n], end = row_ptr[n + 1];

    float Craw = dec_f32(mx[head]) + dec_f32(mx[4 + head]);
    float C = Craw > 0.f ? Craw : 0.2f * Craw;
    float edv = ed[n * 4 + head];

    float acc[8] = {0.f, 0.f, 0.f, 0.f, 0.f, 0.f, 0.f, 0.f};
    float ws = 0.f;
    const __half* hb = hph + (long long)t * 8;

    int i = beg;
    int alim = (beg + 3) & ~3;      // align col pointer to 16B
    for (; i < end && i < alim; ++i) {
        int s = col[i];
        float lv = es[s * 4 + head] + edv;
        lv = lv > 0.f ? lv : 0.2f * lv;
        float w = __expf(lv - C);
        ws += w;
        uint4 gv = *(const uint4*)(hb + (long long)s * 128);
        float2 f;
        f = __half22float2(*(__half2*)&gv.x); acc[0] += w * f.x; acc[1] += w * f.y;
        f = __half22float2(*(__half2*)&gv.y); acc[2] += w * f.x; acc[3] += w * f.y;
        f = __half22float2(*(__half2*)&gv.z); acc[4] += w * f.x; acc[5] += w * f.y;
        f = __half22float2(*(__half2*)&gv.w); acc[6] += w * f.x; acc[7] += w * f.y;
    }
    for (; i + 3 < end; i += 4) {
        int4 s4 = *(const int4*)(col + i);
        float l0 = es[s4.x * 4 + head] + edv;
        float l1 = es[s4.y * 4 + head] + edv;
        float l2 = es[s4.z * 4 + head] + edv;
        float l3 = es[s4.w * 4 + head] + edv;
        uint4 g0 = *(const uint4*)(hb + (long long)s4.x * 128);
        uint4 g1 = *(const uint4*)(hb + (long long)s4.y * 128);
        uint4 g2 = *(const uint4*)(hb + (long long)s4.z * 128);
        uint4 g3 = *(const uint4*)(hb + (long long)s4.w * 128);
        l0 = l0 > 0.f ? l0 : 0.2f * l0;
        l1 = l1 > 0.f ? l1 : 0.2f * l1;
        l2 = l2 > 0.f ? l2 : 0.2f * l2;
        l3 = l3 > 0.f ? l3 : 0.2f * l3;
        float w0 = __expf(l0 - C);
        float w1 = __expf(l1 - C);
        float w2 = __expf(l2 - C);
        float w3 = __expf(l3 - C);
        ws += (w0 + w1) + (w2 + w3);
        float2 f;
        f = __half22float2(*(__half2*)&g0.x); acc[0] += w0 * f.x; acc[1] += w0 * f.y;
        f = __half22float2(*(__half2*)&g0.y); acc[2] += w0 * f.x; acc[3] += w0 * f.y;
        f = __half22float2(*(__half2*)&g0.z); acc[4] += w0 * f.x; acc[5] += w0 * f.y;
        f = __half22float2(*(__half2*)&g0.w); acc[6] += w0 * f.x; acc[7] += w0 * f.y;
        f = __half22float2(*(__half2*)&g1.x); acc[0] += w1 * f.x; acc[1] += w1 * f.y;
        f = __half22float2(*(__half2*)&g1.y); acc[2] += w1 * f.x; acc[3] += w1 * f.y;
        f = __half22float2(*(__half2*)&g1.z); acc[4] += w1 * f.x; acc[5] += w1 * f.y;
        f = __half22float2(*(__half2*)&g1.w); acc[6] += w1 * f.x; acc[7] += w1 * f.y;
        f = __half22float2(*(__half2*)&g2.x); acc[0] += w2 * f.x; acc[1] += w2 * f.y;
        f = __half22float2(*(__half2*)&g2.y); acc[2] += w2 * f.x; acc[3] += w2 * f.y;
        f = __half22float2(*(__half2*)&g2.z); acc[4] += w2 * f.x; acc[5] += w2 * f.y;
        f = __half22float2(*(__half2*)&g2.w); acc[6] += w2 * f.x; acc[7] += w2 * f.y;
        f = __half22float2(*(__half2*)&g3.x); acc[0] += w3 * f.x; acc[1] += w3 * f.y;
        f = __half22float2(*(__half2*)&g3.y); acc[2] += w3 * f.x; acc[3] += w3 * f.y;
        f = __half22float2(*(__half2*)&g3.z); acc[4] += w3 * f.x; acc[5] += w3 * f.y;
        f = __half22float2(*(__half2*)&g3.w); acc[6] += w3 * f.x; acc[7] += w3 * f.y;
    }
    for (; i < end; ++i) {
        int s = col[i];
        float lv = es[s * 4 + head] + edv;
        lv = lv > 0.f ? lv : 0.2f * lv;
        float w = __expf(lv - C);
        ws += w;
        uint4 gv = *(const uint4*)(hb + (long long)s * 128);
        float2 f;
        f = __half22float2(*(__half2*)&gv.x); acc[0] += w * f.x; acc[1] += w * f.y;
        f = __half22float2(*(__half2*)&gv.y); acc[2] += w * f.x; acc[3] += w * f.y;
        f = __half22float2(*(__half2*)&gv.z); acc[4] += w * f.x; acc[5] += w * f.y;
        f = __half22float2(*(__half2*)&gv.w); acc[6] += w * f.x; acc[7] += w * f.y;
    }
    float sv = ws + 1e-16f;
    float vals[8];
    #pragma unroll
    for (int j = 0; j < 8; ++j) {
        float v = acc[j] / sv + b[t * 8 + j];
        vals[j] = v > 0.f ? v : expm1f(v);
    }
    if (outf) {
        float4 v0 = {vals[0], vals[1], vals[2], vals[3]};
        float4 v1 = {vals[4], vals[5], vals[6], vals[7]};
        *(float4*)(outf + (long long)n * 128 + t * 8) = v0;
        *(float4*)(outf + (long long)n * 128 + t * 8 + 4) = v1;
    } else {
        __half o[8];
        #pragma unroll
        for (int j = 0; j < 8; ++j) o[j] = __float2half(vals[j]);
        *(uint4*)(outh + (long long)n * 128 + t * 8) = *(uint4*)o;
    }
}

// ============================ host ============================

extern "C" void kernel_launch(void* const* d_in, const int* in_sizes, int n_in,
                              void* d_out, int out_size, void* d_ws, size_t ws_size,
                              hipStream_t stream) {
    const float* x    = (const float*)d_in[0];
    const int*   ei   = (const int*)d_in[1];
    const float* W_in = (const float*)d_in[2];
    const float* b_in = (const float*)d_in[3];
    const float* W[3]  = {(const float*)d_in[4], (const float*)d_in[8],  (const float*)d_in[12]};
    const float* As[3] = {(const float*)d_in[5], (const float*)d_in[9],  (const float*)d_in[13]};
    const float* Ad[3] = {(const float*)d_in[6], (const float*)d_in[10], (const float*)d_in[14]};
    const float* Bs[3] = {(const float*)d_in[7], (const float*)d_in[11], (const float*)d_in[15]};

    // workspace layout (~77 MB)
    __half*   h0h  = (__half*)d_ws;                       // NN*32 f16
    __half*   hph  = h0h + (size_t)NN * 32;               // NN*128 f16
    __half*   ah   = hph + (size_t)NN * 128;              // NN*128 f16
    _Float16* Wf0  = (_Float16*)(ah + (size_t)NN * 128);  // 512*8 f16
    _Float16* Wf1  = Wf0 + 512 * 8;                       // 2048*8 f16
    _Float16* Wf2  = Wf1 + 2048 * 8;                      // 2048*8 f16
    float*    es   = (float*)(Wf2 + 2048 * 8);            // NN*4
    float*    ed   = es + (size_t)NN * 4;                 // NN*4
    int*   row_ptr = (int*)(ed + (size_t)NN * 4);         // NN+1
    int*    bhist  = row_ptr + (NN + 1);                  // NBK
    int*    bbase  = bhist + NBK;                         // NBK+1
    int*    bcur   = bbase + (NBK + 1);                   // NBK
    unsigned* mx   = (unsigned*)(bcur + NBK);             // 24 (8 per layer)
    unsigned* brec = (unsigned*)(mx + 24);                // ET
    int*    colb   = (int*)(brec + ET);                   // ET

    // ---- CSR build via bucket sort (graph is static across layers) ----
    hipMemsetAsync(bhist, 0, NBK * sizeof(int), stream);
    hipMemsetAsync(mx, 0, 24 * sizeof(unsigned), stream);
    bucket_hist<<<512, 256, 0, stream>>>(ei, bhist);
    bucket_scan<<<1, 256, 0, stream>>>(bhist, bbase, bcur);
    bucket_scatter<<<(ET + EPB - 1) / EPB, 256, 0, stream>>>(ei, bcur, brec);
    bucket_csr<<<NBK, 256, 0, stream>>>(brec, bbase, row_ptr, colb);

    lin_relu2h<<<3125, 256, 0, stream>>>(x, W_in, b_in, h0h);
    wf_prep<1><<<2, 256, 0, stream>>>(W[0], Wf0);
    wf_prep<4><<<8, 256, 0, stream>>>(W[1], Wf1);
    wf_prep<4><<<8, 256, 0, stream>>>(W[2], Wf2);

    // layer 0 (K=32, MFMA)
    gemm_mfma<1><<<782, 256, 0, stream>>>(h0h, Wf0, As[0], Ad[0], hph, es, ed, mx);
    gat_aggregate6<<<6250, 256, 0, stream>>>(row_ptr, colb, es, ed, mx, hph, Bs[0],
                                             nullptr, ah);
    // layer 1 (K=128, MFMA)
    gemm_mfma<4><<<782, 256, 0, stream>>>(ah, Wf1, As[1], Ad[1], hph, es, ed, mx + 8);
    gat_aggregate6<<<6250, 256, 0, stream>>>(row_ptr, colb, es, ed, mx + 8, hph, Bs[1],
                                             nullptr, ah);
    // layer 2 (K=128, MFMA) -> f32 output
    gemm_mfma<4><<<782, 256, 0, stream>>>(ah, Wf2, As[2], Ad[2], hph, es, ed, mx + 16);
    gat_aggregate6<<<6250, 256, 0, stream>>>(row_ptr, colb, es, ed, mx + 16, hph, Bs[2],
                                             (float*)d_out, nullptr);
}

// Round 19
// 489.808 us; speedup vs baseline: 1.0548x; 1.0548x over previous
//
#include <hip/hip_runtime.h>
#include <hip/hip_fp16.h>

#define NN 100000
#define NE 1600000
#define ET (NE + NN)   // edges + self-loops = 1,700,000
#define BKW 512                      // bucket width (nodes); dst>>9
#define NBK ((NN + BKW - 1) / BKW)   // 196 buckets
#define LCOL_CAP 12288               // max edges/bucket
#define EPB 16384                    // edges per scatter block

typedef _Float16 half8_t __attribute__((ext_vector_type(8)));
typedef float f32x4_t __attribute__((ext_vector_type(4)));

// ---- ordered-uint encoding for float atomicMax (bijective, monotone) ----
__device__ __forceinline__ unsigned enc_f32(float v) {
    unsigned b = __float_as_uint(v);
    return b ^ ((b & 0x80000000u) ? 0xFFFFFFFFu : 0x80000000u);
}
__device__ __forceinline__ float dec_f32(unsigned u) {
    unsigned b = (u & 0x80000000u) ? (u ^ 0x80000000u) : ~u;
    return __uint_as_float(b);
}

// ============================ dense layers ============================

// h0 = relu(x @ W_in + b_in), fp16 output. W_in staged in LDS.
__global__ __launch_bounds__(256) void lin_relu2h(const float* __restrict__ x,
                                                  const float* __restrict__ W,
                                                  const float* __restrict__ b,
                                                  __half* __restrict__ h) {
    __shared__ float Wl[256 * 32];
    int t = threadIdx.x;
    for (int j = 0; j < 8; ++j) {
        int f = t + 256 * j;
        *(float4*)&Wl[f * 4] = *(const float4*)(W + f * 4);
    }
    __syncthreads();

    int row = (blockIdx.x * 256 + t) >> 3;
    int c0  = (t & 7) * 4;
    const float* xr = x + (long long)row * 256;
    float4 acc = {0.f, 0.f, 0.f, 0.f};
    for (int k4 = 0; k4 < 64; ++k4) {
        float4 xv = *(const float4*)(xr + k4 * 4);
        float4 w0 = *(const float4*)&Wl[(k4 * 4 + 0) * 32 + c0];
        float4 w1 = *(const float4*)&Wl[(k4 * 4 + 1) * 32 + c0];
        float4 w2 = *(const float4*)&Wl[(k4 * 4 + 2) * 32 + c0];
        float4 w3 = *(const float4*)&Wl[(k4 * 4 + 3) * 32 + c0];
        acc.x += xv.x * w0.x + xv.y * w1.x + xv.z * w2.x + xv.w * w3.x;
        acc.y += xv.x * w0.y + xv.y * w1.y + xv.z * w2.y + xv.w * w3.y;
        acc.z += xv.x * w0.z + xv.y * w1.z + xv.z * w2.z + xv.w * w3.z;
        acc.w += xv.x * w0.w + xv.y * w1.w + xv.z * w2.w + xv.w * w3.w;
    }
    float4 bv = *(const float4*)(b + c0);
    __half2 p0 = __floats2half2_rn(fmaxf(acc.x + bv.x, 0.f), fmaxf(acc.y + bv.y, 0.f));
    __half2 p1 = __floats2half2_rn(fmaxf(acc.z + bv.z, 0.f), fmaxf(acc.w + bv.w, 0.f));
    uint2 pk;
    pk.x = *(unsigned*)&p0;
    pk.y = *(unsigned*)&p1;
    *(uint2*)(h + (long long)row * 32 + c0) = pk;
}

// ---- pack W [K][128] f32 into per-lane MFMA B-fragment order (fp16), K = KS*32 ----
template<int KS>
__global__ __launch_bounds__(256) void wf_prep(const float* __restrict__ W,
                                               _Float16* __restrict__ Wf) {
    int id = blockIdx.x * 256 + threadIdx.x;     // < 8*KS*64
    if (id >= 8 * KS * 64) return;
    int lane = id & 63;
    int q = id >> 6;
    int ks = q % KS;
    int n = q / KS;
    int col = n * 16 + (lane & 15);
    int k0 = ks * 32 + ((lane >> 4) << 3);
    _Float16 tmp[8];
    #pragma unroll
    for (int j = 0; j < 8; ++j) tmp[j] = (_Float16)W[(k0 + j) * 128 + col];
    *(half8_t*)(Wf + (size_t)id * 8) = *(half8_t*)tmp;
}

// ---- MFMA gemm, K = KS*32, N=128. 128 rows/block, 4 waves x 32 rows. ----
// Epilogue via LDS fp16 tile: vectorized hph stores + LDS-dot es/ed (no shfl storm).
#define HLS 136   // LDS row stride in halves (272B -> bank-shift 4/row, 2-way max)
template<int KS>
__global__ __launch_bounds__(256) void gemm_mfma2(const __half* __restrict__ ah,
                                                  const _Float16* __restrict__ Wf,
                                                  const float* __restrict__ asrc,
                                                  const float* __restrict__ adst,
                                                  __half* __restrict__ hph,
                                                  float* __restrict__ es,
                                                  float* __restrict__ ed,
                                                  unsigned* __restrict__ mxl) {
    __shared__ __half hl[128 * HLS];
    __shared__ unsigned lmx[8];
    int t = threadIdx.x;
    if (t < 8) lmx[t] = 0u;

    const int K = KS * 32;
    int lane = t & 63, wid = t >> 6;
    int li = lane & 15, lg = lane >> 4;
    int blk = blockIdx.x * 128;
    int base = blk + wid * 32;
    int r0 = base + li, r1 = r0 + 16;
    long long r0c = min(r0, NN - 1), r1c = min(r1, NN - 1);
    const _Float16* A = (const _Float16*)ah;

    f32x4_t acc[2][8];
    #pragma unroll
    for (int m = 0; m < 2; ++m)
        #pragma unroll
        for (int n = 0; n < 8; ++n) acc[m][n] = (f32x4_t){0.f, 0.f, 0.f, 0.f};

    #pragma unroll
    for (int ks = 0; ks < KS; ++ks) {
        half8_t a0 = *(const half8_t*)(A + r0c * K + ks * 32 + lg * 8);
        half8_t a1 = *(const half8_t*)(A + r1c * K + ks * 32 + lg * 8);
        #pragma unroll
        for (int n = 0; n < 8; ++n) {
            half8_t b = *(const half8_t*)(Wf + (size_t)((n * KS + ks) * 64 + lane) * 8);
            acc[0][n] = __builtin_amdgcn_mfma_f32_16x16x32_f16(a0, b, acc[0][n], 0, 0, 0);
            acc[1][n] = __builtin_amdgcn_mfma_f32_16x16x32_f16(a1, b, acc[1][n], 0, 0, 0);
        }
    }

    // stage C-tile to LDS as fp16 (local rows = wave-local 32-row band)
    int lrow0 = wid * 32;
    #pragma unroll
    for (int m = 0; m < 2; ++m) {
        #pragma unroll
        for (int r = 0; r < 4; ++r) {
            int lr = lrow0 + m * 16 + lg * 4 + r;
            #pragma unroll
            for (int h = 0; h < 4; ++h) {
                hl[lr * HLS + h * 32 + li]      = __float2half(acc[m][2 * h][r]);
                hl[lr * HLS + h * 32 + 16 + li] = __float2half(acc[m][2 * h + 1][r]);
            }
        }
    }
    __syncthreads();

    // phase A: coalesced vectorized hph stores (16B per thread-iter)
    #pragma unroll
    for (int j = 0; j < 8; ++j) {
        int id = t + 256 * j;            // 0..2047
        int row = id >> 4, seg = id & 15;
        int gr = blk + row;
        if (gr < NN)
            *(uint4*)(hph + (long long)gr * 128 + seg * 8) =
                *(const uint4*)&hl[row * HLS + seg * 8];
    }

    // phase B: es/ed dot-products from LDS; per-head block max via LDS atomics
    #pragma unroll
    for (int j = 0; j < 2; ++j) {
        int id = t + 256 * j;            // 0..511
        int row = id >> 2, head = id & 3;
        int gr = blk + row;
        if (gr < NN) {
            float ps = 0.f, pd = 0.f;
            #pragma unroll
            for (int k4 = 0; k4 < 8; ++k4) {
                float4 a4 = *(const float4*)(asrc + head * 32 + k4 * 4);
                float4 d4 = *(const float4*)(adst + head * 32 + k4 * 4);
                __half2 h0 = *(const __half2*)&hl[row * HLS + head * 32 + k4 * 4];
                __half2 h1 = *(const __half2*)&hl[row * HLS + head * 32 + k4 * 4 + 2];
                float2 f0 = __half22float2(h0);
                float2 f1 = __half22float2(h1);
                ps += f0.x * a4.x + f0.y * a4.y + f1.x * a4.z + f1.y * a4.w;
                pd += f0.x * d4.x + f0.y * d4.y + f1.x * d4.z + f1.y * d4.w;
            }
            es[gr * 4 + head] = ps;
            ed[gr * 4 + head] = pd;
            atomicMax(&lmx[head], enc_f32(ps));
            atomicMax(&lmx[4 + head], enc_f32(pd));
        }
    }
    __syncthreads();
    if (t < 8) atomicMax(mxl + t, lmx[t]);
}

// ================== CSR build via 2-level bucket sort (once) ==================

__global__ __launch_bounds__(256) void bucket_hist(const int* __restrict__ ei,
                                                   int* __restrict__ bhist) {
    __shared__ int lh[NBK];
    int t = threadIdx.x;
    for (int i = t; i < NBK; i += 256) lh[i] = 0;
    __syncthreads();
    for (long long e = (long long)blockIdx.x * 256 + t; e < ET; e += (long long)gridDim.x * 256) {
        int dst = (e < NE) ? ei[NE + e] : (int)(e - NE);
        atomicAdd(&lh[dst >> 9], 1);
    }
    __syncthreads();
    for (int i = t; i < NBK; i += 256) if (lh[i]) atomicAdd(&bhist[i], lh[i]);
}

__global__ __launch_bounds__(256) void bucket_scan(const int* __restrict__ bhist,
                                                   int* __restrict__ bbase,
                                                   int* __restrict__ bcur) {
    __shared__ int ls[256];
    int t = threadIdx.x;
    int v = (t < NBK) ? bhist[t] : 0;
    ls[t] = v;
    __syncthreads();
    for (int off = 1; off < 256; off <<= 1) {
        int u = (t >= off) ? ls[t - off] : 0;
        __syncthreads();
        ls[t] += u;
        __syncthreads();
    }
    if (t < NBK) { int b0 = ls[t] - v; bbase[t] = b0; bcur[t] = b0; }
    if (t == 0) bbase[NBK] = ET;
}

__global__ __launch_bounds__(256) void bucket_scatter(const int* __restrict__ ei,
                                                      int* __restrict__ bcur,
                                                      unsigned* __restrict__ brec) {
    __shared__ int lcnt[NBK];
    __shared__ int lbase[NBK];
    int t = threadIdx.x;
    long long e0 = (long long)blockIdx.x * EPB;
    for (int i = t; i < NBK; i += 256) lcnt[i] = 0;
    __syncthreads();
    for (int j = 0; j < EPB / 256; ++j) {
        long long e = e0 + j * 256 + t;
        if (e < ET) {
            int dst = (e < NE) ? ei[NE + e] : (int)(e - NE);
            atomicAdd(&lcnt[dst >> 9], 1);
        }
    }
    __syncthreads();
    for (int i = t; i < NBK; i += 256) {
        int c = lcnt[i];
        lbase[i] = c ? atomicAdd(&bcur[i], c) : 0;
        lcnt[i] = 0;
    }
    __syncthreads();
    for (int j = 0; j < EPB / 256; ++j) {
        long long e = e0 + j * 256 + t;
        if (e < ET) {
            int src, dst;
            if (e < NE) { src = ei[e]; dst = ei[NE + e]; }
            else        { src = dst = (int)(e - NE); }
            int b = dst >> 9;
            int off = atomicAdd(&lcnt[b], 1);
            brec[lbase[b] + off] = ((unsigned)(dst & 511) << 17) | (unsigned)src;
        }
    }
}

__global__ __launch_bounds__(256) void bucket_csr(const unsigned* __restrict__ brec,
                                                  const int* __restrict__ bbase,
                                                  int* __restrict__ row_ptr,
                                                  int* __restrict__ col) {
    __shared__ int ldeg[BKW];
    __shared__ int lrp[BKW + 1];
    __shared__ int lcur[BKW];
    __shared__ int ls[256];
    __shared__ int lcol[LCOL_CAP];
    int t = threadIdx.x, b = blockIdx.x;
    int rbeg = bbase[b], rend = bbase[b + 1];
    int cnt = rend - rbeg;
    for (int i = t; i < BKW; i += 256) ldeg[i] = 0;
    __syncthreads();
    for (int i = t; i < cnt; i += 256) {
        unsigned r = brec[rbeg + i];
        atomicAdd(&ldeg[r >> 17], 1);
    }
    __syncthreads();
    int a0 = ldeg[2 * t], a1 = ldeg[2 * t + 1];
    int pl = a0 + a1;
    ls[t] = pl;
    __syncthreads();
    for (int off = 1; off < 256; off <<= 1) {
        int u = (t >= off) ? ls[t - off] : 0;
        __syncthreads();
        ls[t] += u;
        __syncthreads();
    }
    int eb = ls[t] - pl;
    lrp[2 * t] = eb;
    lrp[2 * t + 1] = eb + a0;
    lcur[2 * t] = eb;
    lcur[2 * t + 1] = eb + a0;
    if (t == 255) lrp[BKW] = ls[255];
    __syncthreads();
    int gn0 = b * BKW;
    int nnb = min(BKW, NN - gn0);
    for (int i = t; i <= nnb; i += 256) row_ptr[gn0 + i] = rbeg + lrp[i];
    for (int i = t; i < cnt; i += 256) {
        unsigned r = brec[rbeg + i];
        int pos = atomicAdd(&lcur[r >> 17], 1);
        lcol[pos] = (int)(r & 0x1FFFFu);
    }
    __syncthreads();
    for (int i = t; i < cnt; i += 256) col[rbeg + i] = lcol[i];
}

// ==================== single-pass softmax-aggregate (fp16 gather) ====================
// 16 lanes/node, lane owns 8 dims. Scalar col loads, 4-way unroll (proven best: 88us).
__global__ __launch_bounds__(256) void gat_aggregate4(
        const int* __restrict__ row_ptr, const int* __restrict__ col,
        const float* __restrict__ es, const float* __restrict__ ed,
        const unsigned* __restrict__ mx, const __half* __restrict__ hph,
        const float* __restrict__ b, float* __restrict__ outf,
        __half* __restrict__ outh) {
    int tid = blockIdx.x * 256 + threadIdx.x;
    int n = tid >> 4;
    int t = tid & 15;
    if (n >= NN) return;
    int head = t >> 2;
    int beg = row_ptr[n], end = row_ptr[n + 1];

    float Craw = dec_f32(mx[head]) + dec_f32(mx[4 + head]);
    float C = Craw > 0.f ? Craw : 0.2f * Craw;
    float edv = ed[n * 4 + head];

    float acc[8] = {0.f, 0.f, 0.f, 0.f, 0.f, 0.f, 0.f, 0.f};
    float ws = 0.f;
    const __half* hb = hph + (long long)t * 8;

    int i = beg;
    for (; i + 3 < end; i += 4) {
        int s0 = col[i], s1 = col[i + 1], s2 = col[i + 2], s3 = col[i + 3];
        float l0 = es[s0 * 4 + head] + edv;
        float l1 = es[s1 * 4 + head] + edv;
        float l2 = es[s2 * 4 + head] + edv;
        float l3 = es[s3 * 4 + head] + edv;
        uint4 g0 = *(const uint4*)(hb + (long long)s0 * 128);
        uint4 g1 = *(const uint4*)(hb + (long long)s1 * 128);
        uint4 g2 = *(const uint4*)(hb + (long long)s2 * 128);
        uint4 g3 = *(const uint4*)(hb + (long long)s3 * 128);
        l0 = l0 > 0.f ? l0 : 0.2f * l0;
        l1 = l1 > 0.f ? l1 : 0.2f * l1;
        l2 = l2 > 0.f ? l2 : 0.2f * l2;
        l3 = l3 > 0.f ? l3 : 0.2f * l3;
        float w0 = __expf(l0 - C);
        float w1 = __expf(l1 - C);
        float w2 = __expf(l2 - C);
        float w3 = __expf(l3 - C);
        ws += (w0 + w1) + (w2 + w3);
        float2 f;
        f = __half22float2(*(__half2*)&g0.x); acc[0] += w0 * f.x; acc[1] += w0 * f.y;
        f = __half22float2(*(__half2*)&g0.y); acc[2] += w0 * f.x; acc[3] += w0 * f.y;
        f = __half22float2(*(__half2*)&g0.z); acc[4] += w0 * f.x; acc[5] += w0 * f.y;
        f = __half22float2(*(__half2*)&g0.w); acc[6] += w0 * f.x; acc[7] += w0 * f.y;
        f = __half22float2(*(__half2*)&g1.x); acc[0] += w1 * f.x; acc[1] += w1 * f.y;
        f = __half22float2(*(__half2*)&g1.y); acc[2] += w1 * f.x; acc[3] += w1 * f.y;
        f = __half22float2(*(__half2*)&g1.z); acc[4] += w1 * f.x; acc[5] += w1 * f.y;
        f = __half22float2(*(__half2*)&g1.w); acc[6] += w1 * f.x; acc[7] += w1 * f.y;
        f = __half22float2(*(__half2*)&g2.x); acc[0] += w2 * f.x; acc[1] += w2 * f.y;
        f = __half22float2(*(__half2*)&g2.y); acc[2] += w2 * f.x; acc[3] += w2 * f.y;
        f = __half22float2(*(__half2*)&g2.z); acc[4] += w2 * f.x; acc[5] += w2 * f.y;
        f = __half22float2(*(__half2*)&g2.w); acc[6] += w2 * f.x; acc[7] += w2 * f.y;
        f = __half22float2(*(__half2*)&g3.x); acc[0] += w3 * f.x; acc[1] += w3 * f.y;
        f = __half22float2(*(__half2*)&g3.y); acc[2] += w3 * f.x; acc[3] += w3 * f.y;
        f = __half22float2(*(__half2*)&g3.z); acc[4] += w3 * f.x; acc[5] += w3 * f.y;
        f = __half22float2(*(__half2*)&g3.w); acc[6] += w3 * f.x; acc[7] += w3 * f.y;
    }
    for (; i < end; ++i) {
        int s = col[i];
        float lv = es[s * 4 + head] + edv;
        lv = lv > 0.f ? lv : 0.2f * lv;
        float w = __expf(lv - C);
        ws += w;
        uint4 g = *(const uint4*)(hb + (long long)s * 128);
        float2 f;
        f = __half22float2(*(__half2*)&g.x); acc[0] += w * f.x; acc[1] += w * f.y;
        f = __half22float2(*(__half2*)&g.y); acc[2] += w * f.x; acc[3] += w * f.y;
        f = __half22float2(*(__half2*)&g.z); acc[4] += w * f.x; acc[5] += w * f.y;
        f = __half22float2(*(__half2*)&g.w); acc[6] += w * f.x; acc[7] += w * f.y;
    }
    float sv = ws + 1e-16f;
    float vals[8];
    #pragma unroll
    for (int j = 0; j < 8; ++j) {
        float v = acc[j] / sv + b[t * 8 + j];
        vals[j] = v > 0.f ? v : expm1f(v);
    }
    if (outf) {
        float4 v0 = {vals[0], vals[1], vals[2], vals[3]};
        float4 v1 = {vals[4], vals[5], vals[6], vals[7]};
        *(float4*)(outf + (long long)n * 128 + t * 8) = v0;
        *(float4*)(outf + (long long)n * 128 + t * 8 + 4) = v1;
    } else {
        __half o[8];
        #pragma unroll
        for (int j = 0; j < 8; ++j) o[j] = __float2half(vals[j]);
        *(uint4*)(outh + (long long)n * 128 + t * 8) = *(uint4*)o;
    }
}

// ============================ host ============================

extern "C" void kernel_launch(void* const* d_in, const int* in_sizes, int n_in,
                              void* d_out, int out_size, void* d_ws, size_t ws_size,
                              hipStream_t stream) {
    const float* x    = (const float*)d_in[0];
    const int*   ei   = (const int*)d_in[1];
    const float* W_in = (const float*)d_in[2];
    const float* b_in = (const float*)d_in[3];
    const float* W[3]  = {(const float*)d_in[4], (const float*)d_in[8],  (const float*)d_in[12]};
    const float* As[3] = {(const float*)d_in[5], (const float*)d_in[9],  (const float*)d_in[13]};
    const float* Ad[3] = {(const float*)d_in[6], (const float*)d_in[10], (const float*)d_in[14]};
    const float* Bs[3] = {(const float*)d_in[7], (const float*)d_in[11], (const float*)d_in[15]};

    // workspace layout (~77 MB)
    __half*   h0h  = (__half*)d_ws;                       // NN*32 f16
    __half*   hph  = h0h + (size_t)NN * 32;               // NN*128 f16
    __half*   ah   = hph + (size_t)NN * 128;              // NN*128 f16
    _Float16* Wf0  = (_Float16*)(ah + (size_t)NN * 128);  // 512*8 f16
    _Float16* Wf1  = Wf0 + 512 * 8;                       // 2048*8 f16
    _Float16* Wf2  = Wf1 + 2048 * 8;                      // 2048*8 f16
    float*    es   = (float*)(Wf2 + 2048 * 8);            // NN*4
    float*    ed   = es + (size_t)NN * 4;                 // NN*4
    int*   row_ptr = (int*)(ed + (size_t)NN * 4);         // NN+1
    int*    bhist  = row_ptr + (NN + 1);                  // NBK
    int*    bbase  = bhist + NBK;                         // NBK+1
    int*    bcur   = bbase + (NBK + 1);                   // NBK
    unsigned* mx   = (unsigned*)(bcur + NBK);             // 24 (8 per layer)
    unsigned* brec = (unsigned*)(mx + 24);                // ET
    int*    colb   = (int*)(brec + ET);                   // ET

    // ---- CSR build via bucket sort (graph is static across layers) ----
    hipMemsetAsync(bhist, 0, NBK * sizeof(int), stream);
    hipMemsetAsync(mx, 0, 24 * sizeof(unsigned), stream);
    bucket_hist<<<512, 256, 0, stream>>>(ei, bhist);
    bucket_scan<<<1, 256, 0, stream>>>(bhist, bbase, bcur);
    bucket_scatter<<<(ET + EPB - 1) / EPB, 256, 0, stream>>>(ei, bcur, brec);
    bucket_csr<<<NBK, 256, 0, stream>>>(brec, bbase, row_ptr, colb);

    lin_relu2h<<<3125, 256, 0, stream>>>(x, W_in, b_in, h0h);
    wf_prep<1><<<2, 256, 0, stream>>>(W[0], Wf0);
    wf_prep<4><<<8, 256, 0, stream>>>(W[1], Wf1);
    wf_prep<4><<<8, 256, 0, stream>>>(W[2], Wf2);

    // layer 0 (K=32, MFMA)
    gemm_mfma2<1><<<782, 256, 0, stream>>>(h0h, Wf0, As[0], Ad[0], hph, es, ed, mx);
    gat_aggregate4<<<6250, 256, 0, stream>>>(row_ptr, colb, es, ed, mx, hph, Bs[0],
                                             nullptr, ah);
    // layer 1 (K=128, MFMA)
    gemm_mfma2<4><<<782, 256, 0, stream>>>(ah, Wf1, As[1], Ad[1], hph, es, ed, mx + 8);
    gat_aggregate4<<<6250, 256, 0, stream>>>(row_ptr, colb, es, ed, mx + 8, hph, Bs[1],
                                             nullptr, ah);
    // layer 2 (K=128, MFMA) -> f32 output
    gemm_mfma2<4><<<782, 256, 0, stream>>>(ah, Wf2, As[2], Ad[2], hph, es, ed, mx + 16);
    gat_aggregate4<<<6250, 256, 0, stream>>>(row_ptr, colb, es, ed, mx + 16, hph, Bs[2],
                                             (float*)d_out, nullptr);
}

// Round 21
// 475.238 us; speedup vs baseline: 1.0872x; 1.0307x over previous
//
#include <hip/hip_runtime.h>
#include <hip/hip_fp16.h>

#define NN 100000
#define NE 1600000
#define ET (NE + NN)   // edges + self-loops = 1,700,000
#define BKW 512                      // bucket width (nodes); dst>>9
#define NBK ((NN + BKW - 1) / BKW)   // 196 buckets
#define LCOL_CAP 12288               // max edges/bucket
#define EPB 16384                    // edges per scatter block

typedef _Float16 half8_t __attribute__((ext_vector_type(8)));
typedef float f32x4_t __attribute__((ext_vector_type(4)));

// ---- ordered-uint encoding for float atomicMax (bijective, monotone) ----
__device__ __forceinline__ unsigned enc_f32(float v) {
    unsigned b = __float_as_uint(v);
    return b ^ ((b & 0x80000000u) ? 0xFFFFFFFFu : 0x80000000u);
}
__device__ __forceinline__ float dec_f32(unsigned u) {
    unsigned b = (u & 0x80000000u) ? (u ^ 0x80000000u) : ~u;
    return __uint_as_float(b);
}

// ============================ dense layers ============================

// h0 = relu(x @ W_in + b_in), fp16 output. W_in staged in LDS.
__global__ __launch_bounds__(256) void lin_relu2h(const float* __restrict__ x,
                                                  const float* __restrict__ W,
                                                  const float* __restrict__ b,
                                                  __half* __restrict__ h) {
    __shared__ float Wl[256 * 32];
    int t = threadIdx.x;
    for (int j = 0; j < 8; ++j) {
        int f = t + 256 * j;
        *(float4*)&Wl[f * 4] = *(const float4*)(W + f * 4);
    }
    __syncthreads();

    int row = (blockIdx.x * 256 + t) >> 3;
    int c0  = (t & 7) * 4;
    const float* xr = x + (long long)row * 256;
    float4 acc = {0.f, 0.f, 0.f, 0.f};
    for (int k4 = 0; k4 < 64; ++k4) {
        float4 xv = *(const float4*)(xr + k4 * 4);
        float4 w0 = *(const float4*)&Wl[(k4 * 4 + 0) * 32 + c0];
        float4 w1 = *(const float4*)&Wl[(k4 * 4 + 1) * 32 + c0];
        float4 w2 = *(const float4*)&Wl[(k4 * 4 + 2) * 32 + c0];
        float4 w3 = *(const float4*)&Wl[(k4 * 4 + 3) * 32 + c0];
        acc.x += xv.x * w0.x + xv.y * w1.x + xv.z * w2.x + xv.w * w3.x;
        acc.y += xv.x * w0.y + xv.y * w1.y + xv.z * w2.y + xv.w * w3.y;
        acc.z += xv.x * w0.z + xv.y * w1.z + xv.z * w2.z + xv.w * w3.z;
        acc.w += xv.x * w0.w + xv.y * w1.w + xv.z * w2.w + xv.w * w3.w;
    }
    float4 bv = *(const float4*)(b + c0);
    __half2 p0 = __floats2half2_rn(fmaxf(acc.x + bv.x, 0.f), fmaxf(acc.y + bv.y, 0.f));
    __half2 p1 = __floats2half2_rn(fmaxf(acc.z + bv.z, 0.f), fmaxf(acc.w + bv.w, 0.f));
    uint2 pk;
    pk.x = *(unsigned*)&p0;
    pk.y = *(unsigned*)&p1;
    *(uint2*)(h + (long long)row * 32 + c0) = pk;
}

// ---- pack W [K][128] f32 into per-lane MFMA B-fragment order (fp16), K = KS*32 ----
template<int KS>
__global__ __launch_bounds__(256) void wf_prep(const float* __restrict__ W,
                                               _Float16* __restrict__ Wf) {
    int id = blockIdx.x * 256 + threadIdx.x;     // < 8*KS*64
    if (id >= 8 * KS * 64) return;
    int lane = id & 63;
    int q = id >> 6;
    int ks = q % KS;
    int n = q / KS;
    int col = n * 16 + (lane & 15);
    int k0 = ks * 32 + ((lane >> 4) << 3);
    _Float16 tmp[8];
    #pragma unroll
    for (int j = 0; j < 8; ++j) tmp[j] = (_Float16)W[(k0 + j) * 128 + col];
    *(half8_t*)(Wf + (size_t)id * 8) = *(half8_t*)tmp;
}

// ---- MFMA gemm, K = KS*32, N=128. 128 rows/block, 4 waves x 32 rows. ----
template<int KS>
__global__ __launch_bounds__(256) void gemm_mfma(const __half* __restrict__ ah,
                                                 const _Float16* __restrict__ Wf,
                                                 const float* __restrict__ asrc,
                                                 const float* __restrict__ adst,
                                                 __half* __restrict__ hph,
                                                 float* __restrict__ es,
                                                 float* __restrict__ ed,
                                                 unsigned* __restrict__ mxl) {
    __shared__ unsigned lmx[8];
    int t = threadIdx.x;
    if (t < 8) lmx[t] = 0u;
    __syncthreads();

    const int K = KS * 32;
    int lane = t & 63, wid = t >> 6;
    int li = lane & 15, lg = lane >> 4;
    int base = blockIdx.x * 128 + wid * 32;
    int r0 = base + li, r1 = r0 + 16;
    long long r0c = min(r0, NN - 1), r1c = min(r1, NN - 1);
    const _Float16* A = (const _Float16*)ah;

    f32x4_t acc[2][8];
    #pragma unroll
    for (int m = 0; m < 2; ++m)
        #pragma unroll
        for (int n = 0; n < 8; ++n) acc[m][n] = (f32x4_t){0.f, 0.f, 0.f, 0.f};

    #pragma unroll
    for (int ks = 0; ks < KS; ++ks) {
        half8_t a0 = *(const half8_t*)(A + r0c * K + ks * 32 + lg * 8);
        half8_t a1 = *(const half8_t*)(A + r1c * K + ks * 32 + lg * 8);
        #pragma unroll
        for (int n = 0; n < 8; ++n) {
            half8_t b = *(const half8_t*)(Wf + (size_t)((n * KS + ks) * 64 + lane) * 8);
            acc[0][n] = __builtin_amdgcn_mfma_f32_16x16x32_f16(a0, b, acc[0][n], 0, 0, 0);
            acc[1][n] = __builtin_amdgcn_mfma_f32_16x16x32_f16(a1, b, acc[1][n], 0, 0, 0);
        }
    }

    float as_lo[4], as_hi[4], ad_lo[4], ad_hi[4];
    #pragma unroll
    for (int h = 0; h < 4; ++h) {
        as_lo[h] = asrc[h * 32 + li];
        as_hi[h] = asrc[h * 32 + 16 + li];
        ad_lo[h] = adst[h * 32 + li];
        ad_hi[h] = adst[h * 32 + 16 + li];
    }

    float smax[4] = {-1e30f, -1e30f, -1e30f, -1e30f};
    float dmax[4] = {-1e30f, -1e30f, -1e30f, -1e30f};
    #pragma unroll
    for (int m = 0; m < 2; ++m) {
        #pragma unroll
        for (int r = 0; r < 4; ++r) {
            int gr = base + m * 16 + lg * 4 + r;
            bool valid = gr < NN;
            float ps[4], pd[4];
            #pragma unroll
            for (int h = 0; h < 4; ++h) {
                float va = acc[m][2 * h][r];
                float vb = acc[m][2 * h + 1][r];
                if (valid) {
                    hph[(long long)gr * 128 + h * 32 + li] = __float2half(va);
                    hph[(long long)gr * 128 + h * 32 + 16 + li] = __float2half(vb);
                }
                ps[h] = va * as_lo[h] + vb * as_hi[h];
                pd[h] = va * ad_lo[h] + vb * ad_hi[h];
            }
            #pragma unroll
            for (int off = 1; off < 16; off <<= 1) {
                #pragma unroll
                for (int h = 0; h < 4; ++h) {
                    ps[h] += __shfl_xor(ps[h], off);
                    pd[h] += __shfl_xor(pd[h], off);
                }
            }
            if (li == 0 && valid) {
                #pragma unroll
                for (int h = 0; h < 4; ++h) {
                    es[gr * 4 + h] = ps[h];
                    ed[gr * 4 + h] = pd[h];
                    smax[h] = fmaxf(smax[h], ps[h]);
                    dmax[h] = fmaxf(dmax[h], pd[h]);
                }
            }
        }
    }
    if (li == 0) {
        #pragma unroll
        for (int h = 0; h < 4; ++h) {
            atomicMax(&lmx[h], enc_f32(smax[h]));
            atomicMax(&lmx[4 + h], enc_f32(dmax[h]));
        }
    }
    __syncthreads();
    if (t < 8) atomicMax(mxl + t, lmx[t]);
}

// ================== CSR build via 2-level bucket sort (once) ==================

__global__ __launch_bounds__(256) void bucket_hist(const int* __restrict__ ei,
                                                   int* __restrict__ bhist) {
    __shared__ int lh[NBK];
    int t = threadIdx.x;
    for (int i = t; i < NBK; i += 256) lh[i] = 0;
    __syncthreads();
    for (long long e = (long long)blockIdx.x * 256 + t; e < ET; e += (long long)gridDim.x * 256) {
        int dst = (e < NE) ? ei[NE + e] : (int)(e - NE);
        atomicAdd(&lh[dst >> 9], 1);
    }
    __syncthreads();
    for (int i = t; i < NBK; i += 256) if (lh[i]) atomicAdd(&bhist[i], lh[i]);
}

__global__ __launch_bounds__(256) void bucket_scan(const int* __restrict__ bhist,
                                                   int* __restrict__ bbase,
                                                   int* __restrict__ bcur) {
    __shared__ int ls[256];
    int t = threadIdx.x;
    int v = (t < NBK) ? bhist[t] : 0;
    ls[t] = v;
    __syncthreads();
    for (int off = 1; off < 256; off <<= 1) {
        int u = (t >= off) ? ls[t - off] : 0;
        __syncthreads();
        ls[t] += u;
        __syncthreads();
    }
    if (t < NBK) { int b0 = ls[t] - v; bbase[t] = b0; bcur[t] = b0; }
    if (t == 0) bbase[NBK] = ET;
}

__global__ __launch_bounds__(256) void bucket_scatter(const int* __restrict__ ei,
                                                      int* __restrict__ bcur,
                                                      unsigned* __restrict__ brec) {
    __shared__ int lcnt[NBK];
    __shared__ int lbase[NBK];
    int t = threadIdx.x;
    long long e0 = (long long)blockIdx.x * EPB;
    for (int i = t; i < NBK; i += 256) lcnt[i] = 0;
    __syncthreads();
    for (int j = 0; j < EPB / 256; ++j) {
        long long e = e0 + j * 256 + t;
        if (e < ET) {
            int dst = (e < NE) ? ei[NE + e] : (int)(e - NE);
            atomicAdd(&lcnt[dst >> 9], 1);
        }
    }
    __syncthreads();
    for (int i = t; i < NBK; i += 256) {
        int c = lcnt[i];
        lbase[i] = c ? atomicAdd(&bcur[i], c) : 0;
        lcnt[i] = 0;
    }
    __syncthreads();
    for (int j = 0; j < EPB / 256; ++j) {
        long long e = e0 + j * 256 + t;
        if (e < ET) {
            int src, dst;
            if (e < NE) { src = ei[e]; dst = ei[NE + e]; }
            else        { src = dst = (int)(e - NE); }
            int b = dst >> 9;
            int off = atomicAdd(&lcnt[b], 1);
            brec[lbase[b] + off] = ((unsigned)(dst & 511) << 17) | (unsigned)src;
        }
    }
}

__global__ __launch_bounds__(256) void bucket_csr(const unsigned* __restrict__ brec,
                                                  const int* __restrict__ bbase,
                                                  int* __restrict__ row_ptr,
                                                  int* __restrict__ col) {
    __shared__ int ldeg[BKW];
    __shared__ int lrp[BKW + 1];
    __shared__ int lcur[BKW];
    __shared__ int ls[256];
    __shared__ int lcol[LCOL_CAP];
    int t = threadIdx.x, b = blockIdx.x;
    int rbeg = bbase[b], rend = bbase[b + 1];
    int cnt = rend - rbeg;
    for (int i = t; i < BKW; i += 256) ldeg[i] = 0;
    __syncthreads();
    for (int i = t; i < cnt; i += 256) {
        unsigned r = brec[rbeg + i];
        atomicAdd(&ldeg[r >> 17], 1);
    }
    __syncthreads();
    int a0 = ldeg[2 * t], a1 = ldeg[2 * t + 1];
    int pl = a0 + a1;
    ls[t] = pl;
    __syncthreads();
    for (int off = 1; off < 256; off <<= 1) {
        int u = (t >= off) ? ls[t - off] : 0;
        __syncthreads();
        ls[t] += u;
        __syncthreads();
    }
    int eb = ls[t] - pl;
    lrp[2 * t] = eb;
    lrp[2 * t + 1] = eb + a0;
    lcur[2 * t] = eb;
    lcur[2 * t + 1] = eb + a0;
    if (t == 255) lrp[BKW] = ls[255];
    __syncthreads();
    int gn0 = b * BKW;
    int nnb = min(BKW, NN - gn0);
    for (int i = t; i <= nnb; i += 256) row_ptr[gn0 + i] = rbeg + lrp[i];
    for (int i = t; i < cnt; i += 256) {
        unsigned r = brec[rbeg + i];
        int pos = atomicAdd(&lcur[r >> 17], 1);
        lcol[pos] = (int)(r & 0x1FFFFu);
    }
    __syncthreads();
    for (int i = t; i < cnt; i += 256) col[rbeg + i] = lcol[i];
}

// ==================== single-pass softmax-aggregate (fp16 gather) ====================
// 16 lanes/node, lane owns 8 dims. Scalar col loads, 4-way unroll (proven best: 88us).
__global__ __launch_bounds__(256) void gat_aggregate4(
        const int* __restrict__ row_ptr, const int* __restrict__ col,
        const float* __restrict__ es, const float* __restrict__ ed,
        const unsigned* __restrict__ mx, const __half* __restrict__ hph,
        const float* __restrict__ b, float* __restrict__ outf,
        __half* __restrict__ outh) {
    int tid = blockIdx.x * 256 + threadIdx.x;
    int n = tid >> 4;
    int t = tid & 15;
    if (n >= NN) return;
    int head = t >> 2;
    int beg = row_ptr[n], end = row_ptr[n + 1];

    float Craw = dec_f32(mx[head]) + dec_f32(mx[4 + head]);
    float C = Craw > 0.f ? Craw : 0.2f * Craw;
    float edv = ed[n * 4 + head];

    float acc[8] = {0.f, 0.f, 0.f, 0.f, 0.f, 0.f, 0.f, 0.f};
    float ws = 0.f;
    const __half* hb = hph + (long long)t * 8;

    int i = beg;
    for (; i + 3 < end; i += 4) {
        int s0 = col[i], s1 = col[i + 1], s2 = col[i + 2], s3 = col[i + 3];
        float l0 = es[s0 * 4 + head] + edv;
        float l1 = es[s1 * 4 + head] + edv;
        float l2 = es[s2 * 4 + head] + edv;
        float l3 = es[s3 * 4 + head] + edv;
        uint4 g0 = *(const uint4*)(hb + (long long)s0 * 128);
        uint4 g1 = *(const uint4*)(hb + (long long)s1 * 128);
        uint4 g2 = *(const uint4*)(hb + (long long)s2 * 128);
        uint4 g3 = *(const uint4*)(hb + (long long)s3 * 128);
        l0 = l0 > 0.f ? l0 : 0.2f * l0;
        l1 = l1 > 0.f ? l1 : 0.2f * l1;
        l2 = l2 > 0.f ? l2 : 0.2f * l2;
        l3 = l3 > 0.f ? l3 : 0.2f * l3;
        float w0 = __expf(l0 - C);
        float w1 = __expf(l1 - C);
        float w2 = __expf(l2 - C);
        float w3 = __expf(l3 - C);
        ws += (w0 + w1) + (w2 + w3);
        float2 f;
        f = __half22float2(*(__half2*)&g0.x); acc[0] += w0 * f.x; acc[1] += w0 * f.y;
        f = __half22float2(*(__half2*)&g0.y); acc[2] += w0 * f.x; acc[3] += w0 * f.y;
        f = __half22float2(*(__half2*)&g0.z); acc[4] += w0 * f.x; acc[5] += w0 * f.y;
        f = __half22float2(*(__half2*)&g0.w); acc[6] += w0 * f.x; acc[7] += w0 * f.y;
        f = __half22float2(*(__half2*)&g1.x); acc[0] += w1 * f.x; acc[1] += w1 * f.y;
        f = __half22float2(*(__half2*)&g1.y); acc[2] += w1 * f.x; acc[3] += w1 * f.y;
        f = __half22float2(*(__half2*)&g1.z); acc[4] += w1 * f.x; acc[5] += w1 * f.y;
        f = __half22float2(*(__half2*)&g1.w); acc[6] += w1 * f.x; acc[7] += w1 * f.y;
        f = __half22float2(*(__half2*)&g2.x); acc[0] += w2 * f.x; acc[1] += w2 * f.y;
        f = __half22float2(*(__half2*)&g2.y); acc[2] += w2 * f.x; acc[3] += w2 * f.y;
        f = __half22float2(*(__half2*)&g2.z); acc[4] += w2 * f.x; acc[5] += w2 * f.y;
        f = __half22float2(*(__half2*)&g2.w); acc[6] += w2 * f.x; acc[7] += w2 * f.y;
        f = __half22float2(*(__half2*)&g3.x); acc[0] += w3 * f.x; acc[1] += w3 * f.y;
        f = __half22float2(*(__half2*)&g3.y); acc[2] += w3 * f.x; acc[3] += w3 * f.y;
        f = __half22float2(*(__half2*)&g3.z); acc[4] += w3 * f.x; acc[5] += w3 * f.y;
        f = __half22float2(*(__half2*)&g3.w); acc[6] += w3 * f.x; acc[7] += w3 * f.y;
    }
    for (; i < end; ++i) {
        int s = col[i];
        float lv = es[s * 4 + head] + edv;
        lv = lv > 0.f ? lv : 0.2f * lv;
        float w = __expf(lv - C);
        ws += w;
        uint4 g = *(const uint4*)(hb + (long long)s * 128);
        float2 f;
        f = __half22float2(*(__half2*)&g.x); acc[0] += w * f.x; acc[1] += w * f.y;
        f = __half22float2(*(__half2*)&g.y); acc[2] += w * f.x; acc[3] += w * f.y;
        f = __half22float2(*(__half2*)&g.z); acc[4] += w * f.x; acc[5] += w * f.y;
        f = __half22float2(*(__half2*)&g.w); acc[6] += w * f.x; acc[7] += w * f.y;
    }
    float sv = ws + 1e-16f;
    float vals[8];
    #pragma unroll
    for (int j = 0; j < 8; ++j) {
        float v = acc[j] / sv + b[t * 8 + j];
        vals[j] = v > 0.f ? v : expm1f(v);
    }
    if (outf) {
        float4 v0 = {vals[0], vals[1], vals[2], vals[3]};
        float4 v1 = {vals[4], vals[5], vals[6], vals[7]};
        *(float4*)(outf + (long long)n * 128 + t * 8) = v0;
        *(float4*)(outf + (long long)n * 128 + t * 8 + 4) = v1;
    } else {
        __half o[8];
        #pragma unroll
        for (int j = 0; j < 8; ++j) o[j] = __float2half(vals[j]);
        *(uint4*)(outh + (long long)n * 128 + t * 8) = *(uint4*)o;
    }
}

// ============================ host ============================

extern "C" void kernel_launch(void* const* d_in, const int* in_sizes, int n_in,
                              void* d_out, int out_size, void* d_ws, size_t ws_size,
                              hipStream_t stream) {
    const float* x    = (const float*)d_in[0];
    const int*   ei   = (const int*)d_in[1];
    const float* W_in = (const float*)d_in[2];
    const float* b_in = (const float*)d_in[3];
    const float* W[3]  = {(const float*)d_in[4], (const float*)d_in[8],  (const float*)d_in[12]};
    const float* As[3] = {(const float*)d_in[5], (const float*)d_in[9],  (const float*)d_in[13]};
    const float* Ad[3] = {(const float*)d_in[6], (const float*)d_in[10], (const float*)d_in[14]};
    const float* Bs[3] = {(const float*)d_in[7], (const float*)d_in[11], (const float*)d_in[15]};

    // workspace layout (~77 MB)
    __half*   h0h  = (__half*)d_ws;                       // NN*32 f16
    __half*   hph  = h0h + (size_t)NN * 32;               // NN*128 f16
    __half*   ah   = hph + (size_t)NN * 128;              // NN*128 f16
    _Float16* Wf0  = (_Float16*)(ah + (size_t)NN * 128);  // 512*8 f16
    _Float16* Wf1  = Wf0 + 512 * 8;                       // 2048*8 f16
    _Float16* Wf2  = Wf1 + 2048 * 8;                      // 2048*8 f16
    float*    es   = (float*)(Wf2 + 2048 * 8);            // NN*4
    float*    ed   = es + (size_t)NN * 4;                 // NN*4
    int*   row_ptr = (int*)(ed + (size_t)NN * 4);         // NN+1
    int*    bhist  = row_ptr + (NN + 1);                  // NBK
    int*    bbase  = bhist + NBK;                         // NBK+1
    int*    bcur   = bbase + (NBK + 1);                   // NBK
    unsigned* mx   = (unsigned*)(bcur + NBK);             // 24 (8 per layer)
    unsigned* brec = (unsigned*)(mx + 24);                // ET
    int*    colb   = (int*)(brec + ET);                   // ET

    // ---- CSR build via bucket sort (graph is static across layers) ----
    hipMemsetAsync(bhist, 0, NBK * sizeof(int), stream);
    hipMemsetAsync(mx, 0, 24 * sizeof(unsigned), stream);
    bucket_hist<<<512, 256, 0, stream>>>(ei, bhist);
    bucket_scan<<<1, 256, 0, stream>>>(bhist, bbase, bcur);
    bucket_scatter<<<(ET + EPB - 1) / EPB, 256, 0, stream>>>(ei, bcur, brec);
    bucket_csr<<<NBK, 256, 0, stream>>>(brec, bbase, row_ptr, colb);

    lin_relu2h<<<3125, 256, 0, stream>>>(x, W_in, b_in, h0h);
    wf_prep<1><<<2, 256, 0, stream>>>(W[0], Wf0);
    wf_prep<4><<<8, 256, 0, stream>>>(W[1], Wf1);
    wf_prep<4><<<8, 256, 0, stream>>>(W[2], Wf2);

    // layer 0 (K=32, MFMA)
    gemm_mfma<1><<<782, 256, 0, stream>>>(h0h, Wf0, As[0], Ad[0], hph, es, ed, mx);
    gat_aggregate4<<<6250, 256, 0, stream>>>(row_ptr, colb, es, ed, mx, hph, Bs[0],
                                             nullptr, ah);
    // layer 1 (K=128, MFMA)
    gemm_mfma<4><<<782, 256, 0, stream>>>(ah, Wf1, As[1], Ad[1], hph, es, ed, mx + 8);
    gat_aggregate4<<<6250, 256, 0, stream>>>(row_ptr, colb, es, ed, mx + 8, hph, Bs[1],
                                             nullptr, ah);
    // layer 2 (K=128, MFMA) -> f32 output
    gemm_mfma<4><<<782, 256, 0, stream>>>(ah, Wf2, As[2], Ad[2], hph, es, ed, mx + 16);
    gat_aggregate4<<<6250, 256, 0, stream>>>(row_ptr, colb, es, ed, mx + 16, hph, Bs[2],
                                             (float*)d_out, nullptr);
}